// Round 3
// baseline (676.377 us; speedup 1.0000x reference)
//
#include <hip/hip_runtime.h>
#include <hip/hip_bf16.h>

// LinkClassifier: out[e] = relu(concat(h[s],h[t],ea,pooled[batch[s]]) @ W1 + b1) @ W2 + b2
// Runtime-detects float32 vs bf16 storage of the float tensors, and int32 vs int64
// storage of ei/batch. MFMA compute in bf16 (RNE-converted), fp32 accumulation.

typedef __attribute__((ext_vector_type(8))) short bf16x8;   // 8 bf16 in 4 VGPRs
typedef __attribute__((ext_vector_type(4))) float f32x4;    // MFMA accumulator

constexpr int kND = 256;   // node feature dim
constexpr int kED = 128;   // edge feature dim
constexpr int kH  = 128;   // hidden dim
constexpr int kIN = 896;   // 3*kND + kED
constexpr int kKT = 7;     // K tiles of 128
constexpr int kB  = 2048;  // NUM_GRAPHS
constexpr int TM  = 128;   // edges per block
constexpr int SX  = 136;   // padded LDS row stride (bf16 elems); rows stay 16B-aligned

__device__ __forceinline__ ushort f2bf(float x) {  // RNE f32 -> bf16
  union { float f; unsigned u; } c; c.f = x;
  unsigned u = c.u + 0x7FFFu + ((c.u >> 16) & 1u);
  return (ushort)(u >> 16);
}
__device__ __forceinline__ float bf2f(ushort x) {
  union { unsigned u; float f; } c; c.u = ((unsigned)x) << 16;
  return c.f;
}
// Detect storage of float tensors from h's first 64 32-bit words. bf16 pairs: the
// low ushort is a well-formed bf16 (exponent in a narrow window). float32: the low
// ushort is random mantissa bits (uniform exponent field).
__device__ __forceinline__ bool data_is_f32(const void* p) {
  const unsigned* u = (const unsigned*)p;
  int cnt = 0;
  #pragma unroll
  for (int i = 0; i < 64; ++i) {
    unsigned e = (u[i] >> 7) & 0xFFu;
    cnt += (e >= 90u && e <= 140u) ? 1 : 0;
  }
  return cnt < 40;
}
// int64 values < 2^31 leave every odd int32 word zero.
__device__ __forceinline__ bool idx_is_64(const int* __restrict__ ei32) {
  return ((ei32[1] | ei32[3] | ei32[5] | ei32[7]) == 0) &&
         ((ei32[0] | ei32[2] | ei32[4] | ei32[6]) != 0);
}
__device__ __forceinline__ float loadf(const void* p, int i, bool isf32) {
  return isf32 ? ((const float*)p)[i] : bf2f(((const ushort*)p)[i]);
}

// ---------------- pooling: per-graph mean of h over sorted batch ----------------
__global__ __launch_bounds__(256) void pool_kernel(
    const void* __restrict__ hv, const int* __restrict__ batch,
    const int* __restrict__ ei, int N, ushort* __restrict__ pooled) {
  const bool isf32 = data_is_f32(hv);
  const bool is64 = idx_is_64(ei);
  int b = blockIdx.x;
  __shared__ int bounds[2];
  if (threadIdx.x < 2) {
    int target = b + (int)threadIdx.x;
    int lo = 0, hi = N;
    while (lo < hi) {
      int mid = (lo + hi) >> 1;
      int v = is64 ? batch[2 * mid] : batch[mid];
      if (v < target) lo = mid + 1; else hi = mid;
    }
    bounds[threadIdx.x] = lo;
  }
  __syncthreads();
  int lo = bounds[0], hi = bounds[1];
  float acc = 0.f;
  if (isf32) {
    const float* hf = (const float*)hv;
    for (int r = lo; r < hi; ++r) acc += hf[(size_t)r * kND + threadIdx.x];
  } else {
    const ushort* hu = (const ushort*)hv;
    for (int r = lo; r < hi; ++r) acc += bf2f(hu[(size_t)r * kND + threadIdx.x]);
  }
  int cnt = hi - lo; if (cnt < 1) cnt = 1;
  pooled[(size_t)b * kND + threadIdx.x] = f2bf(acc / (float)cnt);
}

// ---------------- W1 [896][128] -> W1t bf16 [128][896] ----------------
__global__ __launch_bounds__(256) void transpose_w1(
    const void* __restrict__ W1v, const void* __restrict__ hv,
    ushort* __restrict__ W1t) {
  const bool isf32 = data_is_f32(hv);
  int idx = blockIdx.x * 256 + threadIdx.x;
  if (idx < kIN * kH) {
    int n = idx / kIN, k = idx - n * kIN;
    W1t[idx] = isf32 ? f2bf(((const float*)W1v)[k * kH + n])
                     : ((const ushort*)W1v)[k * kH + n];
  }
}

// ---------------- fused edge MLP: gather + GEMM(MFMA) + relu + dot(W2) ----------------
__global__ __launch_bounds__(256, 2) void edge_kernel(
    const void* __restrict__ hv, const int* __restrict__ ei,
    const void* __restrict__ eav, const int* __restrict__ batch,
    const ushort* __restrict__ pooled, const ushort* __restrict__ W1t,
    const void* __restrict__ b1v, const void* __restrict__ W2v,
    const void* __restrict__ b2v, void* __restrict__ outv, int E) {
  __shared__ __align__(16) ushort smem[2 * TM * SX];  // X tile | W tile; reused for hid
  __shared__ int rs[TM], rt[TM], rg[TM];
  __shared__ float w2s[kH], b1s[kH];

  ushort* Xl = smem;
  ushort* Wl = smem + TM * SX;

  const int tid = threadIdx.x;
  const int e0 = blockIdx.x * TM;
  const bool isf32 = data_is_f32(hv);
  const bool is64 = idx_is_64(ei);

  if (tid < TM) {  // TM == kH == 128
    int e = e0 + tid; if (e >= E) e = E - 1;
    int s = is64 ? ei[2 * e] : ei[e];
    int t = is64 ? ei[2 * (E + e)] : ei[E + e];
    rs[tid] = s;
    rt[tid] = t;
    rg[tid] = is64 ? batch[2 * s] : batch[s];
    w2s[tid] = loadf(W2v, tid, isf32);
    b1s[tid] = loadf(b1v, tid, isf32);
  }
  __syncthreads();

  const int wave = tid >> 6, lane = tid & 63;
  const int l15 = lane & 15, quad = lane >> 4;
  const int mh = (wave & 1) * 64;   // edge-half for this wave
  const int nh = (wave >> 1) * 64;  // hidden-half for this wave

  f32x4 acc[4][4];
  #pragma unroll
  for (int i = 0; i < 4; ++i)
    #pragma unroll
    for (int j = 0; j < 4; ++j)
      acc[i][j] = (f32x4){0.f, 0.f, 0.f, 0.f};

  const int r0 = tid >> 4;        // 16 threads per row, 16 rows per pass
  const int c8 = (tid & 15) * 8;  // 8 bf16 (or 8 f32) per thread

  for (int kt = 0; kt < kKT; ++kt) {
    #pragma unroll
    for (int i = 0; i < 8; ++i) {
      int r = r0 + i * 16;
      uint4 val;
      if (kt >= 5) {  // pooled: always bf16 (ours)
        val = *(const uint4*)&pooled[(size_t)rg[r] * kND + (kt - 5) * 128 + c8];
      } else {
        const void* bp; size_t off;
        if (kt < 2)      { bp = hv; off = (size_t)rs[r] * kND + kt * 128 + c8; }
        else if (kt < 4) { bp = hv; off = (size_t)rt[r] * kND + (kt - 2) * 128 + c8; }
        else             { int e = e0 + r; if (e >= E) e = E - 1;
                           bp = eav; off = (size_t)e * kED + c8; }
        if (isf32) {
          const float* s = (const float*)bp + off;
          float4 f0 = ((const float4*)s)[0];
          float4 f1 = ((const float4*)s)[1];
          union { ushort us[8]; uint4 v; } cv;
          cv.us[0] = f2bf(f0.x); cv.us[1] = f2bf(f0.y);
          cv.us[2] = f2bf(f0.z); cv.us[3] = f2bf(f0.w);
          cv.us[4] = f2bf(f1.x); cv.us[5] = f2bf(f1.y);
          cv.us[6] = f2bf(f1.z); cv.us[7] = f2bf(f1.w);
          val = cv.v;
        } else {
          val = *(const uint4*)((const ushort*)bp + off);
        }
      }
      *(uint4*)&Xl[r * SX + c8] = val;
      *(uint4*)&Wl[r * SX + c8] =
          *(const uint4*)(W1t + (size_t)r * kIN + kt * 128 + c8);
    }
    __syncthreads();
    #pragma unroll
    for (int ks = 0; ks < 4; ++ks) {
      int kk = ks * 32 + quad * 8;
      bf16x8 af[4], bfm[4];
      #pragma unroll
      for (int mi = 0; mi < 4; ++mi)
        af[mi] = *(const bf16x8*)&Xl[(mh + mi * 16 + l15) * SX + kk];
      #pragma unroll
      for (int ni = 0; ni < 4; ++ni)
        bfm[ni] = *(const bf16x8*)&Wl[(nh + ni * 16 + l15) * SX + kk];
      #pragma unroll
      for (int mi = 0; mi < 4; ++mi)
        #pragma unroll
        for (int ni = 0; ni < 4; ++ni)
          acc[mi][ni] = __builtin_amdgcn_mfma_f32_16x16x32_bf16(
              af[mi], bfm[ni], acc[mi][ni], 0, 0, 0);
    }
    __syncthreads();
  }

  // ---- epilogue: hid -> LDS (C/D layout: col n = lane&15, row m = quad*4 + reg) ----
  float* hid = (float*)smem;          // [128][132] floats fits in smem
  const int SH = 132;
  #pragma unroll
  for (int mi = 0; mi < 4; ++mi)
    #pragma unroll
    for (int ni = 0; ni < 4; ++ni)
      #pragma unroll
      for (int j = 0; j < 4; ++j) {
        int m = mh + mi * 16 + quad * 4 + j;
        int n = nh + ni * 16 + l15;
        float v = acc[mi][ni][j] + b1s[n];
        hid[m * SH + n] = v > 0.f ? v : 0.f;
      }
  __syncthreads();

  if (tid < TM) {
    float a = 0.f;
    #pragma unroll 8
    for (int n = 0; n < kH; ++n) a += hid[tid * SH + n] * w2s[n];
    a += loadf(b2v, 0, isf32);
    int e = e0 + tid;
    if (e < E) {
      if (isf32) ((float*)outv)[e] = a;
      else       ((ushort*)outv)[e] = f2bf(a);
    }
  }
}

extern "C" void kernel_launch(void* const* d_in, const int* in_sizes, int n_in,
                              void* d_out, int out_size, void* d_ws, size_t ws_size,
                              hipStream_t stream) {
  const void* h   = d_in[0];
  const int*  ei  = (const int*)d_in[1];
  const void* ea  = d_in[2];
  const int*  bat = (const int*)d_in[3];
  const void* W1  = d_in[4];
  const void* b1  = d_in[5];
  const void* W2  = d_in[6];
  const void* b2  = d_in[7];

  const int N = in_sizes[3];
  const int E = in_sizes[1] / 2;

  // workspace: pooled bf16 [2048][256] (1 MB), then W1t bf16 [128][896] (224 KB)
  ushort* pooled = (ushort*)d_ws;
  ushort* W1t = pooled + (size_t)kB * kND;

  pool_kernel<<<kB, 256, 0, stream>>>(h, bat, ei, N, pooled);
  transpose_w1<<<(kIN * kH + 255) / 256, 256, 0, stream>>>(W1, h, W1t);
  edge_kernel<<<(E + TM - 1) / TM, 256, 0, stream>>>(
      h, ei, ea, bat, pooled, W1t, b1, W2, b2, d_out, E);
}

// Round 4
// 553.033 us; speedup vs baseline: 1.2230x; 1.2230x over previous
//
#include <hip/hip_runtime.h>
#include <hip/hip_bf16.h>

// LinkClassifier: out[e] = relu(concat(h[s],h[t],ea,pooled[batch[s]]) @ W1 + b1) @ W2 + b2
// Inputs detected at runtime: float tensors f32-vs-bf16 (h's bit patterns), indices
// int32-vs-int64 (odd-word test). MFMA bf16, fp32 accumulation.
// R4: h pre-converted to bf16 (ws), W1 pre-packed into per-wave fragment order
// (coalesced L2 loads, no W LDS tile -> 38KB LDS -> 4 blocks/CU), shfl epilogue,
// vectorized 4-row-stream pooling.

typedef __attribute__((ext_vector_type(8))) short bf16x8;
typedef __attribute__((ext_vector_type(4))) float f32x4;

constexpr int kND = 256;
constexpr int kED = 128;
constexpr int kH  = 128;
constexpr int kIN = 896;
constexpr int kKT = 7;     // K tiles of 128
constexpr int kB  = 2048;  // NUM_GRAPHS
constexpr int TM  = 128;   // edges per block
constexpr int SX  = 136;   // padded LDS row stride (bf16 elems)
constexpr int kNF = 224;   // W frag-sets: 28 ks * 2 nh * 4 ni

__device__ __forceinline__ ushort f2bf(float x) {
  union { float f; unsigned u; } c; c.f = x;
  unsigned u = c.u + 0x7FFFu + ((c.u >> 16) & 1u);
  return (ushort)(u >> 16);
}
__device__ __forceinline__ float bf2f(ushort x) {
  union { unsigned u; float f; } c; c.u = ((unsigned)x) << 16;
  return c.f;
}
__device__ __forceinline__ bool data_is_f32(const void* p) {
  const unsigned* u = (const unsigned*)p;
  int cnt = 0;
  #pragma unroll
  for (int i = 0; i < 64; ++i) {
    unsigned e = (u[i] >> 7) & 0xFFu;
    cnt += (e >= 90u && e <= 140u) ? 1 : 0;
  }
  return cnt < 40;
}
__device__ __forceinline__ bool idx_is_64(const int* __restrict__ p) {
  return ((p[1] | p[3] | p[5] | p[7]) == 0) && ((p[0] | p[2] | p[4] | p[6]) != 0);
}
__device__ __forceinline__ float loadf(const void* p, int i, bool isf32) {
  return isf32 ? ((const float*)p)[i] : bf2f(((const ushort*)p)[i]);
}

// ---------------- h (f32 or bf16) -> hbf (bf16), grid-stride ----------------
__global__ __launch_bounds__(256) void convert_h(
    const void* __restrict__ hv, ushort* __restrict__ hbf, long total4) {
  const bool isf32 = data_is_f32(hv);
  long i = (long)blockIdx.x * 256 + threadIdx.x;
  const long stride = (long)gridDim.x * 256;
  if (isf32) {
    const float4* src = (const float4*)hv;
    for (; i < total4; i += stride) {
      float4 f = src[i];
      ushort4 u; u.x = f2bf(f.x); u.y = f2bf(f.y); u.z = f2bf(f.z); u.w = f2bf(f.w);
      ((ushort4*)hbf)[i] = u;
    }
  } else {
    const ushort4* src = (const ushort4*)hv;
    for (; i < total4; i += stride) ((ushort4*)hbf)[i] = src[i];
  }
}

// ---------------- pooling: per-graph mean, 4 row-streams x 64 dim-groups ----------------
__global__ __launch_bounds__(256) void pool_kernel(
    const void* __restrict__ hv, const ushort* __restrict__ hbf, int preconv,
    const int* __restrict__ batch, const int* __restrict__ ei, int N,
    ushort* __restrict__ pooled) {
  const bool isf32 = data_is_f32(hv);
  const bool is64 = idx_is_64(ei);
  const int b = blockIdx.x, tid = threadIdx.x;
  __shared__ int bounds[2];
  __shared__ float4 sred[256];
  if (tid < 2) {
    int target = b + tid;
    int lo = 0, hi = N;
    while (lo < hi) {
      int mid = (lo + hi) >> 1;
      int v = is64 ? batch[2 * mid] : batch[mid];
      if (v < target) lo = mid + 1; else hi = mid;
    }
    bounds[tid] = lo;
  }
  __syncthreads();
  const int lo = bounds[0], hi = bounds[1];
  const int dg = tid & 63;    // dims dg*4 .. dg*4+3
  const int rstr = tid >> 6;  // row stream 0..3
  float4 acc = {0.f, 0.f, 0.f, 0.f};
  const ushort* hp = preconv ? hbf : (isf32 ? nullptr : (const ushort*)hv);
  if (hp) {
    for (int r = lo + rstr; r < hi; r += 4) {
      ushort4 u = *(const ushort4*)(hp + (size_t)r * kND + dg * 4);
      acc.x += bf2f(u.x); acc.y += bf2f(u.y); acc.z += bf2f(u.z); acc.w += bf2f(u.w);
    }
  } else {
    const float* hf = (const float*)hv;
    for (int r = lo + rstr; r < hi; r += 4) {
      float4 f = *(const float4*)(hf + (size_t)r * kND + dg * 4);
      acc.x += f.x; acc.y += f.y; acc.z += f.z; acc.w += f.w;
    }
  }
  sred[tid] = acc;
  __syncthreads();
  if (tid < 64) {
    float4 a0 = sred[tid], a1 = sred[tid + 64], a2 = sred[tid + 128], a3 = sred[tid + 192];
    int cnt = hi - lo; if (cnt < 1) cnt = 1;
    float inv = 1.f / (float)cnt;
    ushort4 u;
    u.x = f2bf((a0.x + a1.x + a2.x + a3.x) * inv);
    u.y = f2bf((a0.y + a1.y + a2.y + a3.y) * inv);
    u.z = f2bf((a0.z + a1.z + a2.z + a3.z) * inv);
    u.w = f2bf((a0.w + a1.w + a2.w + a3.w) * inv);
    *(ushort4*)(pooled + (size_t)b * kND + tid * 4) = u;
  }
}

// ---------------- W1 [896][128] -> Wfrag: per-wave B-fragment order ----------------
// frag-set f = ((ksg*2)+nhi)*4+ni ; lane l holds B[n=nhi*64+ni*16+(l&15)][k=ksg*32+(l>>4)*8+j]
__global__ __launch_bounds__(256) void build_wfrag(
    const void* __restrict__ W1v, ushort* __restrict__ Wfrag) {
  const bool isf32 = data_is_f32(W1v);
  int idx = blockIdx.x * 256 + threadIdx.x;
  if (idx >= kNF * 64) return;
  int l = idx & 63, f = idx >> 6;
  int ni = f & 3, nhi = (f >> 2) & 1, ksg = f >> 3;
  int n = nhi * 64 + ni * 16 + (l & 15);
  int k0 = ksg * 32 + (l >> 4) * 8;
  union { ushort us[8]; uint4 v; } cv;
  #pragma unroll
  for (int j = 0; j < 8; ++j)
    cv.us[j] = f2bf(loadf(W1v, (k0 + j) * kH + n, isf32));
  *(uint4*)(Wfrag + (size_t)f * 512 + l * 8) = cv.v;
}

// ---------------- fused edge MLP: gather + GEMM(MFMA) + relu + dot(W2) ----------------
__global__ __launch_bounds__(256, 4) void edge_kernel(
    const void* __restrict__ hv, const ushort* __restrict__ hbf, int preconv,
    const int* __restrict__ ei, const void* __restrict__ eav,
    const int* __restrict__ batch, const ushort* __restrict__ pooled,
    const ushort* __restrict__ Wfrag, const void* __restrict__ b1v,
    const void* __restrict__ W2v, const void* __restrict__ b2v,
    void* __restrict__ outv, int E) {
  __shared__ __align__(16) ushort Xl[TM * SX];  // 34816 B
  __shared__ int rs[TM], rt[TM], rg[TM];
  __shared__ float outacc[TM];
  __shared__ float b1s[kH], w2s[kH];

  const int tid = threadIdx.x;
  const int e0 = blockIdx.x * TM;
  const bool isf32 = data_is_f32(hv);
  const bool is64 = idx_is_64(ei);

  if (tid < TM) {
    int e = e0 + tid; if (e >= E) e = E - 1;
    int s = is64 ? ei[2 * e] : ei[e];
    int t = is64 ? ei[2 * (E + e)] : ei[E + e];
    rs[tid] = s;
    rt[tid] = t;
    rg[tid] = is64 ? batch[2 * s] : batch[s];
    w2s[tid] = loadf(W2v, tid, isf32);
    b1s[tid] = loadf(b1v, tid, isf32);
    outacc[tid] = 0.f;
  }
  __syncthreads();

  const int wave = tid >> 6, lane = tid & 63;
  const int l15 = lane & 15, quad = lane >> 4;
  const int mh = (wave & 1) * 64;     // edge-half for this wave
  const int nhi = wave >> 1;          // hidden-half index
  const int nh = nhi * 64;

  f32x4 acc[4][4];
  #pragma unroll
  for (int i = 0; i < 4; ++i)
    #pragma unroll
    for (int j = 0; j < 4; ++j)
      acc[i][j] = (f32x4){0.f, 0.f, 0.f, 0.f};

  const int r0 = tid >> 4;
  const int c8 = (tid & 15) * 8;
  const ushort* hp = preconv ? hbf : (isf32 ? nullptr : (const ushort*)hv);

  for (int kt = 0; kt < kKT; ++kt) {
    // ---- stage gathered X tile into LDS ----
    #pragma unroll
    for (int i = 0; i < 8; ++i) {
      int r = r0 + i * 16;
      uint4 val;
      if (kt >= 5) {
        val = *(const uint4*)&pooled[(size_t)rg[r] * kND + (kt - 5) * 128 + c8];
      } else if (kt == 4) {
        int e = e0 + r; if (e >= E) e = E - 1;
        if (isf32) {
          const float* s = (const float*)eav + (size_t)e * kED + c8;
          float4 f0 = ((const float4*)s)[0];
          float4 f1 = ((const float4*)s)[1];
          union { ushort us[8]; uint4 v; } cv;
          cv.us[0] = f2bf(f0.x); cv.us[1] = f2bf(f0.y);
          cv.us[2] = f2bf(f0.z); cv.us[3] = f2bf(f0.w);
          cv.us[4] = f2bf(f1.x); cv.us[5] = f2bf(f1.y);
          cv.us[6] = f2bf(f1.z); cv.us[7] = f2bf(f1.w);
          val = cv.v;
        } else {
          val = *(const uint4*)((const ushort*)eav + (size_t)e * kED + c8);
        }
      } else {
        int node = (kt < 2) ? rs[r] : rt[r];
        size_t off = (size_t)node * kND + (kt & 1) * 128 + c8;
        if (hp) {
          val = *(const uint4*)(hp + off);
        } else {
          const float* s = (const float*)hv + off;
          float4 f0 = ((const float4*)s)[0];
          float4 f1 = ((const float4*)s)[1];
          union { ushort us[8]; uint4 v; } cv;
          cv.us[0] = f2bf(f0.x); cv.us[1] = f2bf(f0.y);
          cv.us[2] = f2bf(f0.z); cv.us[3] = f2bf(f0.w);
          cv.us[4] = f2bf(f1.x); cv.us[5] = f2bf(f1.y);
          cv.us[6] = f2bf(f1.z); cv.us[7] = f2bf(f1.w);
          val = cv.v;
        }
      }
      *(uint4*)&Xl[r * SX + c8] = val;
    }
    __syncthreads();
    // ---- 4 MFMA K-steps; B-frags stream coalesced from L2-resident Wfrag ----
    #pragma unroll
    for (int ks = 0; ks < 4; ++ks) {
      const ushort* wp =
          Wfrag + ((size_t)(((kt * 4 + ks) * 2 + nhi) * 4)) * 512 + lane * 8;
      bf16x8 af[4], bfm[4];
      #pragma unroll
      for (int ni = 0; ni < 4; ++ni)
        bfm[ni] = *(const bf16x8*)(wp + ni * 512);
      int kk = ks * 32 + quad * 8;
      #pragma unroll
      for (int mi = 0; mi < 4; ++mi)
        af[mi] = *(const bf16x8*)&Xl[(mh + mi * 16 + l15) * SX + kk];
      #pragma unroll
      for (int mi = 0; mi < 4; ++mi)
        #pragma unroll
        for (int ni = 0; ni < 4; ++ni)
          acc[mi][ni] = __builtin_amdgcn_mfma_f32_16x16x32_bf16(
              af[mi], bfm[ni], acc[mi][ni], 0, 0, 0);
    }
    __syncthreads();
  }

  // ---- epilogue: sum_n relu(hid + b1) * W2 via shfl over the 16 n-lanes ----
  // C/D layout: col n = lane&15, row m = quad*4 + reg
  float w2v[4], b1r[4];
  #pragma unroll
  for (int ni = 0; ni < 4; ++ni) {
    int n = nh + ni * 16 + l15;
    w2v[ni] = w2s[n];
    b1r[ni] = b1s[n];
  }
  #pragma unroll
  for (int mi = 0; mi < 4; ++mi) {
    float ps[4] = {0.f, 0.f, 0.f, 0.f};
    #pragma unroll
    for (int ni = 0; ni < 4; ++ni)
      #pragma unroll
      for (int j = 0; j < 4; ++j) {
        float v = acc[mi][ni][j] + b1r[ni];
        ps[j] += (v > 0.f ? v : 0.f) * w2v[ni];
      }
    #pragma unroll
    for (int off = 1; off < 16; off <<= 1)
      #pragma unroll
      for (int j = 0; j < 4; ++j)
        ps[j] += __shfl_xor(ps[j], off, 64);
    if (l15 == 0)
      #pragma unroll
      for (int j = 0; j < 4; ++j)
        atomicAdd(&outacc[mh + mi * 16 + quad * 4 + j], ps[j]);
  }
  __syncthreads();
  if (tid < TM) {
    int e = e0 + tid;
    if (e < E) {
      float a = outacc[tid] + loadf(b2v, 0, isf32);
      if (isf32) ((float*)outv)[e] = a;
      else       ((ushort*)outv)[e] = f2bf(a);
    }
  }
}

extern "C" void kernel_launch(void* const* d_in, const int* in_sizes, int n_in,
                              void* d_out, int out_size, void* d_ws, size_t ws_size,
                              hipStream_t stream) {
  const void* h   = d_in[0];
  const int*  ei  = (const int*)d_in[1];
  const void* ea  = d_in[2];
  const int*  bat = (const int*)d_in[3];
  const void* W1  = d_in[4];
  const void* b1  = d_in[5];
  const void* W2  = d_in[6];
  const void* b2  = d_in[7];

  const int N = in_sizes[3];
  const int E = in_sizes[1] / 2;

  // ws layout: pooled bf16 [2048][256] | Wfrag bf16 [224*64*8] | hbf bf16 [N][256]
  ushort* pooled = (ushort*)d_ws;
  ushort* Wfrag  = pooled + (size_t)kB * kND;
  ushort* hbf    = Wfrag + (size_t)kNF * 512;
  const size_t need =
      ((size_t)kB * kND + (size_t)kNF * 512 + (size_t)N * kND) * sizeof(ushort);
  const int preconv = (ws_size >= need) ? 1 : 0;

  if (preconv)
    convert_h<<<4096, 256, 0, stream>>>(h, hbf, (long)N * kND / 4);
  pool_kernel<<<kB, 256, 0, stream>>>(h, hbf, preconv, bat, ei, N, pooled);
  build_wfrag<<<(kNF * 64 + 255) / 256, 256, 0, stream>>>(W1, Wfrag);
  edge_kernel<<<(E + TM - 1) / TM, 256, 0, stream>>>(
      h, hbf, preconv, ei, ea, bat, pooled, Wfrag, b1, W2, b2, d_out, E);
}